// Round 9
// baseline (5137.286 us; speedup 1.0000x reference)
//
#include <hip/hip_runtime.h>
#include <cstdint>
#include <cstddef>

// Problem constants (from reference)
constexpr int N_NODES = 100000;
constexpr int N_EDGES = 1000000;

// ---- bf16 pack/unpack (RNE) ----
__device__ __forceinline__ unsigned bf16rne(float f) {
    unsigned u = __float_as_uint(f);
    return (u + 0x7FFFu + ((u >> 16) & 1u)) >> 16;
}
__device__ __forceinline__ unsigned pack2(float lo, float hi) {
    return bf16rne(lo) | (bf16rne(hi) << 16);
}
__device__ __forceinline__ float unpack_lo(unsigned u) { return __uint_as_float(u << 16); }
__device__ __forceinline__ float unpack_hi(unsigned u) { return __uint_as_float(u & 0xFFFF0000u); }

// ============================ CSR build ============================
__global__ void zero_int(int* __restrict__ p, int n) {
    int i = blockIdx.x * blockDim.x + threadIdx.x;
    if (i < n) p[i] = 0;
}

__global__ void hist_kernel(const int* __restrict__ dst, int* __restrict__ cnt) {
    int i = blockIdx.x * blockDim.x + threadIdx.x;
    if (i < N_EDGES) atomicAdd(&cnt[dst[i]], 1);
}

__global__ __launch_bounds__(256) void scan1(const int* __restrict__ cnt,
    int* __restrict__ excl, int* __restrict__ bsum, int n) {
    __shared__ int sh[256];
    int b = blockIdx.x, t = threadIdx.x;
    int base = b * 1024 + t * 4;
    int v0 = (base + 0 < n) ? cnt[base + 0] : 0;
    int v1 = (base + 1 < n) ? cnt[base + 1] : 0;
    int v2 = (base + 2 < n) ? cnt[base + 2] : 0;
    int v3 = (base + 3 < n) ? cnt[base + 3] : 0;
    int s = v0 + v1 + v2 + v3;
    sh[t] = s;
    __syncthreads();
    for (int off = 1; off < 256; off <<= 1) {
        int val = (t >= off) ? sh[t - off] : 0;
        __syncthreads();
        sh[t] += val;
        __syncthreads();
    }
    int prefix = sh[t] - s;
    if (t == 255) bsum[b] = sh[255];
    if (base + 0 < n) excl[base + 0] = prefix;
    if (base + 1 < n) excl[base + 1] = prefix + v0;
    if (base + 2 < n) excl[base + 2] = prefix + v0 + v1;
    if (base + 3 < n) excl[base + 3] = prefix + v0 + v1 + v2;
}

__global__ __launch_bounds__(128) void scan2(int* __restrict__ bsum, int nb) {
    __shared__ int sh[128];
    int t = threadIdx.x;
    int v = (t < nb) ? bsum[t] : 0;
    sh[t] = v;
    __syncthreads();
    for (int off = 1; off < 128; off <<= 1) {
        int val = (t >= off) ? sh[t - off] : 0;
        __syncthreads();
        sh[t] += val;
        __syncthreads();
    }
    if (t < nb) bsum[t] = sh[t] - v;
}

__global__ void scan3(const int* __restrict__ excl, const int* __restrict__ bsum,
                      int* __restrict__ rowptr, int* __restrict__ cursor, int n) {
    int i = blockIdx.x * blockDim.x + threadIdx.x;
    if (i < n) { int r = excl[i] + bsum[i >> 10]; rowptr[i] = r; cursor[i] = r; }
    if (i == n) rowptr[n] = N_EDGES;
}

// scatter (edge id, src node) as one int2 into dst-sorted order
__global__ void scatter_kernel(const int* __restrict__ dst, const int* __restrict__ src,
                               int* __restrict__ cursor, int2* __restrict__ es) {
    int e = blockIdx.x * blockDim.x + threadIdx.x;
    if (e < N_EDGES) {
        int p = atomicAdd(&cursor[dst[e]], 1);
        es[p] = make_int2(e, src[e]);
    }
}

// ============================ Wg build (both layers, one launch) ============================
template<int KDIM, int H>
__device__ void wg_dev(const float* __restrict__ Wq, const float* __restrict__ bq,
                       const float* __restrict__ We,
                       float* __restrict__ Wg, float* __restrict__ bg) {
    __shared__ float wq[KDIM * 64];
    __shared__ float we[32 * 64];
    int t = threadIdx.x;
    for (int i = t; i < KDIM * 64; i += 256) wq[i] = Wq[i];
    for (int i = t; i < 32 * 64; i += 256) we[i] = We[i];
    __syncthreads();
    for (int idx = t; idx < KDIM * 64; idx += 256) {
        int K = idx >> 6, col = idx & 63;
        float s = 0.f;
        if (H == 2) {
            int h = col >> 5, j = col & 31;
            #pragma unroll 8
            for (int c = 0; c < 32; ++c)
                s = fmaf(wq[K * 64 + h * 32 + c], we[j * 64 + h * 32 + c], s);
        } else {
            int j = col;
            if (j < 32) {
                #pragma unroll 8
                for (int c = 0; c < 64; ++c)
                    s = fmaf(wq[K * 64 + c], we[j * 64 + c], s);
            }
        }
        Wg[idx] = s;
    }
    if (t < 64) {
        float s = 0.f;
        if (H == 2) {
            int h = t >> 5, j = t & 31;
            for (int c = 0; c < 32; ++c)
                s = fmaf(bq[h * 32 + c], we[j * 64 + h * 32 + c], s);
        } else {
            if (t < 32)
                for (int c = 0; c < 64; ++c)
                    s = fmaf(bq[c], we[t * 64 + c], s);
        }
        bg[t] = s;
    }
}

__global__ __launch_bounds__(256) void wg_build_both(
    const float* __restrict__ Wq1, const float* __restrict__ bq1,
    const float* __restrict__ We1, float* __restrict__ Wg1, float* __restrict__ bg1,
    const float* __restrict__ Wq2, const float* __restrict__ bq2,
    const float* __restrict__ We2, float* __restrict__ Wg2, float* __restrict__ bg2)
{
    if (blockIdx.x == 0) wg_dev<128, 2>(Wq1, bq1, We1, Wg1, bg1);
    else                 wg_dev<64, 1>(Wq2, bq2, We2, Wg2, bg2);
}

// ============================ fused node GEMM ============================
// ONE block per 64-row tile computes ALL FIVE outputs (q,g,k,v,skip), with the
// full-K x-tile resident in LDS (x read from global exactly once).
// Outputs: qgp = pack(q,g) bf16x2, kvp = pack(k,v) bf16x2, sk fp32.
// BM=64, BN=64, 256 threads, 4x4 microtile; As[K][66] (b64 a-reads, pad-2).
template<int K>
__global__ __launch_bounds__(256) void node_gemm(
    const float* __restrict__ x,
    const float* __restrict__ Wq, const float* __restrict__ bq,
    const float* __restrict__ Wk, const float* __restrict__ bk,
    const float* __restrict__ Wv, const float* __restrict__ bv,
    const float* __restrict__ Ws, const float* __restrict__ bs,
    const float* __restrict__ Wg, const float* __restrict__ bg,
    unsigned* __restrict__ qgp, unsigned* __restrict__ kvp,
    float* __restrict__ sk, int N)
{
    __shared__ float As[K][66];    // x tile transposed: As[k][m], pad 2
    __shared__ float Bs[32][68];   // W k-slab: Bs[k][n], pad 4

    int t  = threadIdx.x;
    int m0 = blockIdx.x * 64;
    constexpr int CQ = K / 4;                    // float4 per row

    // ---- stage full x tile (coalesced; store transposed) ----
    #pragma unroll
    for (int it = 0; it < 64 * CQ / 256; ++it) {
        int idx  = it * 256 + t;
        int row  = idx / CQ, colq = idx % CQ;
        int grow = min(m0 + row, N - 1);
        float4 xv = *(const float4*)&x[(size_t)grow * K + colq * 4];
        #pragma unroll
        for (int c = 0; c < 4; ++c) As[colq * 4 + c][row] = ((const float*)&xv)[c];
    }
    __syncthreads();

    int tx = t & 15, ty = t >> 4;                // cols tx*4, rows ty*4
    float hold[4][4];                            // q (or k) held for packing

    #pragma unroll
    for (int mat = 0; mat < 5; ++mat) {
        const float* W; const float* bvec;
        switch (mat) {
            case 0:  W = Wq; bvec = bq; break;
            case 1:  W = Wg; bvec = bg; break;
            case 2:  W = Wk; bvec = bk; break;
            case 3:  W = Wv; bvec = bv; break;
            default: W = Ws; bvec = bs; break;
        }

        float acc[4][4] = {};
        for (int k0 = 0; k0 < K; k0 += 32) {
            #pragma unroll
            for (int i = 0; i < 2; ++i) {
                int kr = ty + 16 * i;
                *(float4*)&Bs[kr][tx * 4] = *(const float4*)&W[(size_t)(k0 + kr) * 64 + tx * 4];
            }
            __syncthreads();
            #pragma unroll
            for (int kk = 0; kk < 32; ++kk) {
                float2 a0 = *(const float2*)&As[k0 + kk][ty * 4];
                float2 a1 = *(const float2*)&As[k0 + kk][ty * 4 + 2];
                float4 bb = *(const float4*)&Bs[kk][tx * 4];
                float av[4] = {a0.x, a0.y, a1.x, a1.y};
                #pragma unroll
                for (int i = 0; i < 4; ++i)
                    #pragma unroll
                    for (int j = 0; j < 4; ++j)
                        acc[i][j] = fmaf(av[i], ((const float*)&bb)[j], acc[i][j]);
            }
            __syncthreads();
        }

        float4 bias = *(const float4*)&bvec[tx * 4];
        float res[4][4];
        #pragma unroll
        for (int i = 0; i < 4; ++i)
            #pragma unroll
            for (int j = 0; j < 4; ++j)
                res[i][j] = acc[i][j] + ((const float*)&bias)[j];

        if (mat == 0 || mat == 2) {              // hold q / k
            #pragma unroll
            for (int i = 0; i < 4; ++i)
                #pragma unroll
                for (int j = 0; j < 4; ++j) hold[i][j] = res[i][j];
        } else if (mat == 1 || mat == 3) {       // pack (q,g) / (k,v)
            unsigned* dstp = (mat == 1) ? qgp : kvp;
            #pragma unroll
            for (int i = 0; i < 4; ++i) {
                int m = m0 + ty * 4 + i;
                if (m < N) {
                    uint4 u;
                    u.x = pack2(hold[i][0], res[i][0]);
                    u.y = pack2(hold[i][1], res[i][1]);
                    u.z = pack2(hold[i][2], res[i][2]);
                    u.w = pack2(hold[i][3], res[i][3]);
                    *(uint4*)&dstp[(size_t)m * 64 + tx * 4] = u;
                }
            }
        } else {                                 // skip: fp32
            #pragma unroll
            for (int i = 0; i < 4; ++i) {
                int m = m0 + ty * 4 + i;
                if (m < N) {
                    float4 r = {res[i][0], res[i][1], res[i][2], res[i][3]};
                    *(float4*)&sk[(size_t)m * 64 + tx * 4] = r;
                }
            }
        }
    }
}

// ============================ CSR edge pass v5 ============================
// alpha = scale*(q.k[s] + ef.g[d]);  out_pre = (Σ ex*v[s] + (Σ ex*ef)@We)/Σ ex
// kvp/qgp are bf16-packed: ONE dword gather per edge yields both k and v.
// Depth-2 software pipeline; nt hints on single-use streams.
template<int C, int CHUNK>
__global__ __launch_bounds__(256) void edge_csr(
    const int* __restrict__ rowptr, const int2* __restrict__ es,
    const float* __restrict__ ef, const float* __restrict__ We,
    const unsigned* __restrict__ qgp, const unsigned* __restrict__ kvp,
    const float* __restrict__ sk, float* __restrict__ out,
    float scale, int do_relu)
{
    __shared__ float Wel[32 * 64];
    __shared__ float exl[4][64];
    int t = threadIdx.x;
    for (int i = t; i < 32 * 64; i += 256) Wel[i] = We[i];
    __syncthreads();

    int lane  = t & 63;
    int wslot = t >> 6;
    int col   = lane & 31;
    int hsel  = (C == 64) ? 0 : (lane >> 5);

    int wid = blockIdx.x * 4 + wslot;
    int nw  = gridDim.x * 4;

    for (int d0 = wid; d0 < N_NODES; d0 += nw) {
        int d = __builtin_amdgcn_readfirstlane(d0);
        int r0 = rowptr[d], r1 = rowptr[d + 1];
        unsigned uqg = __builtin_nontemporal_load(&qgp[(size_t)d * 64 + lane]);
        float qv = unpack_lo(uqg), gv = unpack_hi(uqg);
        float racc = 0.f, efacc = 0.f, rden = 0.f;

        for (int c0 = r0; c0 < r1; c0 += CHUNK) {
            int rem = min(CHUNK, r1 - c0);
            long long ll = (lane < rem)
                ? __builtin_nontemporal_load((const long long*)&es[c0 + lane]) : 0LL;
            int e_l = (int)ll;
            int s_l = (int)(ll >> 32);

            int i1 = min(1, rem - 1);
            int eA = __builtin_amdgcn_readlane(e_l, 0);
            int sA = __builtin_amdgcn_readlane(s_l, 0);
            int eB = __builtin_amdgcn_readlane(e_l, i1);
            int sB = __builtin_amdgcn_readlane(s_l, i1);
            float    efA = __builtin_nontemporal_load(&ef[(size_t)eA * 32 + col]);
            unsigned uA  = kvp[(size_t)sA * 64 + lane];
            float    efB = __builtin_nontemporal_load(&ef[(size_t)eB * 32 + col]);
            unsigned uB  = kvp[(size_t)sB * 64 + lane];

            for (int i = 0; i < rem; i += 2) {
                int iN0 = min(i + 2, rem - 1);
                int iN1 = min(i + 3, rem - 1);
                int eN0 = __builtin_amdgcn_readlane(e_l, iN0);
                int sN0 = __builtin_amdgcn_readlane(s_l, iN0);
                int eN1 = __builtin_amdgcn_readlane(e_l, iN1);
                int sN1 = __builtin_amdgcn_readlane(s_l, iN1);
                float    efN0 = __builtin_nontemporal_load(&ef[(size_t)eN0 * 32 + col]);
                unsigned uN0  = kvp[(size_t)sN0 * 64 + lane];
                float    efN1 = __builtin_nontemporal_load(&ef[(size_t)eN1 * 32 + col]);
                unsigned uN1  = kvp[(size_t)sN1 * 64 + lane];

                // consume edge i
                {
                    float kk = unpack_lo(uA), vv = unpack_hi(uA);
                    float p = fmaf(qv, kk, efA * gv);
                    #pragma unroll
                    for (int off = C >> 1; off; off >>= 1) p += __shfl_xor(p, off, 64);
                    float ex = __expf(p * scale);
                    racc  = fmaf(vv,  ex, racc);
                    efacc = fmaf(efA, ex, efacc);
                    rden += ex;
                }
                // consume edge i+1
                if (i + 1 < rem) {
                    float kk = unpack_lo(uB), vv = unpack_hi(uB);
                    float p = fmaf(qv, kk, efB * gv);
                    #pragma unroll
                    for (int off = C >> 1; off; off >>= 1) p += __shfl_xor(p, off, 64);
                    float ex = __expf(p * scale);
                    racc  = fmaf(vv,  ex, racc);
                    efacc = fmaf(efB, ex, efacc);
                    rden += ex;
                }

                efA = efN0; uA = uN0;
                efB = efN1; uB = uN1;
            }
        }

        // finalize: (racc + efacc @ We) / rden + skip
        exl[wslot][lane] = efacc;
        float mv = 0.f;
        #pragma unroll 8
        for (int j = 0; j < 32; ++j)
            mv = fmaf(exl[wslot][hsel * 32 + j], Wel[j * 64 + lane], mv);
        float val = (racc + mv) / (rden + 1e-16f)
                  + __builtin_nontemporal_load(&sk[(size_t)d * 64 + lane]);
        if (do_relu) val = fmaxf(val, 0.f);
        __builtin_nontemporal_store(val, &out[(size_t)d * 64 + lane]);
    }
}

extern "C" void kernel_launch(void* const* d_in, const int* in_sizes, int n_in,
                              void* d_out, int out_size, void* d_ws, size_t ws_size,
                              hipStream_t stream) {
    const float* x   = (const float*)d_in[0];
    const int*   ei  = (const int*)d_in[1];
    const float* ef  = (const float*)d_in[2];
    const float* Wq1 = (const float*)d_in[3];  const float* bq1 = (const float*)d_in[4];
    const float* Wk1 = (const float*)d_in[5];  const float* bk1 = (const float*)d_in[6];
    const float* Wv1 = (const float*)d_in[7];  const float* bv1 = (const float*)d_in[8];
    const float* We1 = (const float*)d_in[9];
    const float* Ws1 = (const float*)d_in[10]; const float* bs1 = (const float*)d_in[11];
    const float* Wq2 = (const float*)d_in[12]; const float* bq2 = (const float*)d_in[13];
    const float* Wk2 = (const float*)d_in[14]; const float* bk2 = (const float*)d_in[15];
    const float* Wv2 = (const float*)d_in[16]; const float* bv2 = (const float*)d_in[17];
    const float* We2 = (const float*)d_in[18];
    const float* Ws2 = (const float*)d_in[19]; const float* bs2 = (const float*)d_in[20];
    float* out = (float*)d_out;

    const int N = N_NODES, E = N_EDGES;
    size_t NF = (size_t)N * 64;
    unsigned* qgp = (unsigned*)d_ws;        // N*64 (bf16 q|g packed)
    unsigned* kvp = qgp + NF;               // N*64 (bf16 k|v packed)
    float* sk    = (float*)(kvp + NF);      // N*64
    float* Wg1   = sk + NF;                 // 128*64
    float* bg1   = Wg1 + 128 * 64;          // 64
    float* Wg2   = bg1 + 64;                // 64*64
    float* bg2   = Wg2 + 64 * 64;           // 64
    int* cnt     = (int*)(bg2 + 64);        // N
    int* excl    = cnt + N;                 // N
    int* bsum    = excl + N;                // 128
    int* rowptr  = bsum + 128;              // N+1
    int* cursor  = rowptr + N + 1;          // N
    int2* es     = (int2*)(cursor + N);     // E (edge id | src)
    float* h1    = out;                     // layer-1 output aliases d_out

    const int* src = ei;
    const int* dst = ei + E;

    dim3 b256(256);
    int gN    = (N + 255) / 256;
    int gN1   = (N + 1 + 255) / 256;
    int gE    = (E + 255) / 256;
    int gGemm = (N + 63) / 64;              // one block per 64-row tile (all 5 mats)
    int gEdge = 2048;                       // 8192 persistent waves
    int nScanB = (N + 1023) / 1024;         // 98

    // ---------------- CSR build (shared by both layers) ----------------
    hipLaunchKernelGGL(zero_int, dim3(gN), b256, 0, stream, cnt, N);
    hipLaunchKernelGGL(hist_kernel, dim3(gE), b256, 0, stream, dst, cnt);
    hipLaunchKernelGGL(scan1, dim3(nScanB), b256, 0, stream, cnt, excl, bsum, N);
    hipLaunchKernelGGL(scan2, dim3(1), dim3(128), 0, stream, bsum, nScanB);
    hipLaunchKernelGGL(scan3, dim3(gN1), b256, 0, stream, excl, bsum, rowptr, cursor, N);
    hipLaunchKernelGGL(scatter_kernel, dim3(gE), b256, 0, stream, dst, src, cursor, es);

    // ---------------- weight contractions (one launch, 2 blocks) ----------------
    hipLaunchKernelGGL(wg_build_both, dim3(2), b256, 0, stream,
                       Wq1, bq1, We1, Wg1, bg1, Wq2, bq2, We2, Wg2, bg2);

    // ---------------- layer 1: H=2, C=32, K=128 ----------------
    hipLaunchKernelGGL((node_gemm<128>), dim3(gGemm), b256, 0, stream, x,
                       Wq1, bq1, Wk1, bk1, Wv1, bv1, Ws1, bs1, Wg1, bg1,
                       qgp, kvp, sk, N);
    hipLaunchKernelGGL((edge_csr<32, 16>), dim3(gEdge), b256, 0, stream,
                       rowptr, es, ef, We1, qgp, kvp, sk, h1,
                       0.17677669529663687f, 1);

    // ---------------- layer 2: H=1, C=64, K=64 ----------------
    hipLaunchKernelGGL((node_gemm<64>), dim3(gGemm), b256, 0, stream, h1,
                       Wq2, bq2, Wk2, bk2, Wv2, bv2, Ws2, bs2, Wg2, bg2,
                       qgp, kvp, sk, N);
    hipLaunchKernelGGL((edge_csr<64, 16>), dim3(gEdge), b256, 0, stream,
                       rowptr, es, ef, We2, qgp, kvp, sk, out,
                       0.125f, 0);
}

// Round 10
// 547.987 us; speedup vs baseline: 9.3748x; 9.3748x over previous
//
#include <hip/hip_runtime.h>
#include <cstdint>
#include <cstddef>

// Problem constants (from reference)
constexpr int N_NODES = 100000;
constexpr int N_EDGES = 1000000;

// ---- bf16 pack/unpack (RNE) ----
__device__ __forceinline__ unsigned bf16rne(float f) {
    unsigned u = __float_as_uint(f);
    return (u + 0x7FFFu + ((u >> 16) & 1u)) >> 16;
}
__device__ __forceinline__ unsigned pack2(float lo, float hi) {
    return bf16rne(lo) | (bf16rne(hi) << 16);
}
__device__ __forceinline__ float unpack_lo(unsigned u) { return __uint_as_float(u << 16); }
__device__ __forceinline__ float unpack_hi(unsigned u) { return __uint_as_float(u & 0xFFFF0000u); }

// ============================ CSR build ============================
__global__ void zero_int(int* __restrict__ p, int n) {
    int i = blockIdx.x * blockDim.x + threadIdx.x;
    if (i < n) p[i] = 0;
}

__global__ void hist_kernel(const int* __restrict__ dst, int* __restrict__ cnt) {
    int i = blockIdx.x * blockDim.x + threadIdx.x;
    if (i < N_EDGES) atomicAdd(&cnt[dst[i]], 1);
}

__global__ __launch_bounds__(256) void scan1(const int* __restrict__ cnt,
    int* __restrict__ excl, int* __restrict__ bsum, int n) {
    __shared__ int sh[256];
    int b = blockIdx.x, t = threadIdx.x;
    int base = b * 1024 + t * 4;
    int v0 = (base + 0 < n) ? cnt[base + 0] : 0;
    int v1 = (base + 1 < n) ? cnt[base + 1] : 0;
    int v2 = (base + 2 < n) ? cnt[base + 2] : 0;
    int v3 = (base + 3 < n) ? cnt[base + 3] : 0;
    int s = v0 + v1 + v2 + v3;
    sh[t] = s;
    __syncthreads();
    for (int off = 1; off < 256; off <<= 1) {
        int val = (t >= off) ? sh[t - off] : 0;
        __syncthreads();
        sh[t] += val;
        __syncthreads();
    }
    int prefix = sh[t] - s;
    if (t == 255) bsum[b] = sh[255];
    if (base + 0 < n) excl[base + 0] = prefix;
    if (base + 1 < n) excl[base + 1] = prefix + v0;
    if (base + 2 < n) excl[base + 2] = prefix + v0 + v1;
    if (base + 3 < n) excl[base + 3] = prefix + v0 + v1 + v2;
}

__global__ __launch_bounds__(128) void scan2(int* __restrict__ bsum, int nb) {
    __shared__ int sh[128];
    int t = threadIdx.x;
    int v = (t < nb) ? bsum[t] : 0;
    sh[t] = v;
    __syncthreads();
    for (int off = 1; off < 128; off <<= 1) {
        int val = (t >= off) ? sh[t - off] : 0;
        __syncthreads();
        sh[t] += val;
        __syncthreads();
    }
    if (t < nb) bsum[t] = sh[t] - v;
}

__global__ void scan3(const int* __restrict__ excl, const int* __restrict__ bsum,
                      int* __restrict__ rowptr, int* __restrict__ cursor, int n) {
    int i = blockIdx.x * blockDim.x + threadIdx.x;
    if (i < n) { int r = excl[i] + bsum[i >> 10]; rowptr[i] = r; cursor[i] = r; }
    if (i == n) rowptr[n] = N_EDGES;
}

// scatter (edge id, src node) as one int2 into dst-sorted order
__global__ void scatter_kernel(const int* __restrict__ dst, const int* __restrict__ src,
                               int* __restrict__ cursor, int2* __restrict__ es) {
    int e = blockIdx.x * blockDim.x + threadIdx.x;
    if (e < N_EDGES) {
        int p = atomicAdd(&cursor[dst[e]], 1);
        es[p] = make_int2(e, src[e]);
    }
}

// ============================ Wg build (both layers, one launch) ============================
template<int KDIM, int H>
__device__ void wg_dev(const float* __restrict__ Wq, const float* __restrict__ bq,
                       const float* __restrict__ We,
                       float* __restrict__ Wg, float* __restrict__ bg) {
    __shared__ float wq[KDIM * 64];
    __shared__ float we[32 * 64];
    int t = threadIdx.x;
    for (int i = t; i < KDIM * 64; i += 256) wq[i] = Wq[i];
    for (int i = t; i < 32 * 64; i += 256) we[i] = We[i];
    __syncthreads();
    for (int idx = t; idx < KDIM * 64; idx += 256) {
        int K = idx >> 6, col = idx & 63;
        float s = 0.f;
        if (H == 2) {
            int h = col >> 5, j = col & 31;
            #pragma unroll 8
            for (int c = 0; c < 32; ++c)
                s = fmaf(wq[K * 64 + h * 32 + c], we[j * 64 + h * 32 + c], s);
        } else {
            int j = col;
            if (j < 32) {
                #pragma unroll 8
                for (int c = 0; c < 64; ++c)
                    s = fmaf(wq[K * 64 + c], we[j * 64 + c], s);
            }
        }
        Wg[idx] = s;
    }
    if (t < 64) {
        float s = 0.f;
        if (H == 2) {
            int h = t >> 5, j = t & 31;
            for (int c = 0; c < 32; ++c)
                s = fmaf(bq[h * 32 + c], we[j * 64 + h * 32 + c], s);
        } else {
            if (t < 32)
                for (int c = 0; c < 64; ++c)
                    s = fmaf(bq[c], we[t * 64 + c], s);
        }
        bg[t] = s;
    }
}

__global__ __launch_bounds__(256) void wg_build_both(
    const float* __restrict__ Wq1, const float* __restrict__ bq1,
    const float* __restrict__ We1, float* __restrict__ Wg1, float* __restrict__ bg1,
    const float* __restrict__ Wq2, const float* __restrict__ bq2,
    const float* __restrict__ We2, float* __restrict__ Wg2, float* __restrict__ bg2)
{
    if (blockIdx.x == 0) wg_dev<128, 2>(Wq1, bq1, We1, Wg1, bg1);
    else                 wg_dev<64, 1>(Wq2, bq2, We2, Wg2, bg2);
}

// ============================ node GEMM (round-8 proven) ============================
// o = x@W + b, FIVE weight sets selected by block (q, g, k, v, skip);
// q/g interleave into qg[N][128], k/v into kv[N][128].
// BM=128, BN=64, BK=32, 256 threads, 8x4 microtile.
template<int K>
__global__ __launch_bounds__(256) void node_gemm(
    const float* __restrict__ x,
    const float* __restrict__ Wq, const float* __restrict__ bq,
    const float* __restrict__ Wk, const float* __restrict__ bk,
    const float* __restrict__ Wv, const float* __restrict__ bv,
    const float* __restrict__ Ws, const float* __restrict__ bs,
    const float* __restrict__ Wg, const float* __restrict__ bg,
    float* __restrict__ qg, float* __restrict__ kv,
    float* __restrict__ sk, int N)
{
    __shared__ float As[32][128];  // x tile, transposed: As[k][m]
    __shared__ float Bs[32][64];   // W tile: Bs[k][n]

    int bid = blockIdx.x;
    int mt  = bid / 5;
    int mat = bid % 5;
    const float* W; const float* b; float* o; int ldo;
    switch (mat) {
        case 0:  W = Wq; b = bq; o = qg;      ldo = 128; break;
        case 1:  W = Wg; b = bg; o = qg + 64; ldo = 128; break;
        case 2:  W = Wk; b = bk; o = kv;      ldo = 128; break;
        case 3:  W = Wv; b = bv; o = kv + 64; ldo = 128; break;
        default: W = Ws; b = bs; o = sk;      ldo = 64;  break;
    }

    int t = threadIdx.x;
    int m0 = mt * 128;
    int tx = t & 15, ty = t >> 4;      // 16 col-groups x 16 row-groups(8 rows)
    int rl = t & 127;                  // load row within tile
    int kh = t >> 7;                   // 0/1
    int row = min(m0 + rl, N - 1);

    float acc[8][4] = {};

    for (int k0 = 0; k0 < K; k0 += 32) {
        #pragma unroll
        for (int i = 0; i < 4; ++i) {
            int kq = kh + 2 * i;       // 0..7
            float4 xv = *(const float4*)&x[(size_t)row * K + k0 + kq * 4];
            #pragma unroll
            for (int c = 0; c < 4; ++c) As[kq * 4 + c][rl] = ((const float*)&xv)[c];
        }
        #pragma unroll
        for (int i = 0; i < 2; ++i) {
            int kr = ty + 16 * i;
            *(float4*)&Bs[kr][tx * 4] = *(const float4*)&W[(size_t)(k0 + kr) * 64 + tx * 4];
        }
        __syncthreads();
        #pragma unroll
        for (int kk = 0; kk < 32; ++kk) {
            float4 a0 = *(const float4*)&As[kk][ty * 8];
            float4 a1 = *(const float4*)&As[kk][ty * 8 + 4];
            float4 bb = *(const float4*)&Bs[kk][tx * 4];
            #pragma unroll
            for (int i = 0; i < 4; ++i)
                #pragma unroll
                for (int j = 0; j < 4; ++j) {
                    acc[i][j]     = fmaf(((const float*)&a0)[i], ((const float*)&bb)[j], acc[i][j]);
                    acc[i + 4][j] = fmaf(((const float*)&a1)[i], ((const float*)&bb)[j], acc[i + 4][j]);
                }
        }
        __syncthreads();
    }

    float4 bias = *(const float4*)&b[tx * 4];
    #pragma unroll
    for (int i = 0; i < 8; ++i) {
        int m = m0 + ty * 8 + i;
        if (m < N) {
            float4 r;
            #pragma unroll
            for (int j = 0; j < 4; ++j) ((float*)&r)[j] = acc[i][j] + ((const float*)&bias)[j];
            *(float4*)&o[(size_t)m * ldo + tx * 4] = r;
        }
    }
}

// ============================ kv -> bf16 pack ============================
// kvp[n][c] = pack(bf16(k[n][c]), bf16(v[n][c])) -- one dword per channel so the
// edge pass gathers k AND v with a single 4B load.
__global__ __launch_bounds__(256) void pack_kv(const float* __restrict__ kv,
                                               unsigned* __restrict__ kvp) {
    int i = blockIdx.x * blockDim.x + threadIdx.x;   // over N*16 float4-groups
    if (i >= N_NODES * 16) return;
    int n = i >> 4, cq = i & 15;
    float4 a = *(const float4*)&kv[(size_t)n * 128 + cq * 4];        // k
    float4 b = *(const float4*)&kv[(size_t)n * 128 + 64 + cq * 4];   // v
    uint4 u;
    u.x = pack2(a.x, b.x); u.y = pack2(a.y, b.y);
    u.z = pack2(a.z, b.z); u.w = pack2(a.w, b.w);
    *(uint4*)&kvp[(size_t)n * 64 + cq * 4] = u;
}

// ============================ CSR edge pass v6 ============================
// alpha = scale*(q.k[s] + ef.g[d]);  out_pre = (Σ ex*v[s] + (Σ ex*ef)@We)/Σ ex
// kvp bf16-packed: ONE dword gather per edge yields both k and v; q/g fp32
// (read once per node). Depth-2 software pipeline; nt hints on single-use streams.
template<int C, int CHUNK>
__global__ __launch_bounds__(256) void edge_csr(
    const int* __restrict__ rowptr, const int2* __restrict__ es,
    const float* __restrict__ ef, const float* __restrict__ We,
    const float* __restrict__ qg, const unsigned* __restrict__ kvp,
    const float* __restrict__ sk, float* __restrict__ out,
    float scale, int do_relu)
{
    __shared__ float Wel[32 * 64];
    __shared__ float exl[4][64];
    int t = threadIdx.x;
    for (int i = t; i < 32 * 64; i += 256) Wel[i] = We[i];
    __syncthreads();

    int lane  = t & 63;
    int wslot = t >> 6;
    int col   = lane & 31;
    int hsel  = (C == 64) ? 0 : (lane >> 5);

    int wid = blockIdx.x * 4 + wslot;
    int nw  = gridDim.x * 4;

    for (int d0 = wid; d0 < N_NODES; d0 += nw) {
        int d = __builtin_amdgcn_readfirstlane(d0);
        int r0 = rowptr[d], r1 = rowptr[d + 1];
        float qv = __builtin_nontemporal_load(&qg[(size_t)d * 128 + lane]);
        float gv = __builtin_nontemporal_load(&qg[(size_t)d * 128 + 64 + lane]);
        float racc = 0.f, efacc = 0.f, rden = 0.f;

        for (int c0 = r0; c0 < r1; c0 += CHUNK) {
            int rem = min(CHUNK, r1 - c0);
            long long ll = (lane < rem)
                ? __builtin_nontemporal_load((const long long*)&es[c0 + lane]) : 0LL;
            int e_l = (int)ll;
            int s_l = (int)(ll >> 32);

            int i1 = min(1, rem - 1);
            int eA = __builtin_amdgcn_readlane(e_l, 0);
            int sA = __builtin_amdgcn_readlane(s_l, 0);
            int eB = __builtin_amdgcn_readlane(e_l, i1);
            int sB = __builtin_amdgcn_readlane(s_l, i1);
            float    efA = __builtin_nontemporal_load(&ef[(size_t)eA * 32 + col]);
            unsigned uA  = kvp[(size_t)sA * 64 + lane];
            float    efB = __builtin_nontemporal_load(&ef[(size_t)eB * 32 + col]);
            unsigned uB  = kvp[(size_t)sB * 64 + lane];

            for (int i = 0; i < rem; i += 2) {
                int iN0 = min(i + 2, rem - 1);
                int iN1 = min(i + 3, rem - 1);
                int eN0 = __builtin_amdgcn_readlane(e_l, iN0);
                int sN0 = __builtin_amdgcn_readlane(s_l, iN0);
                int eN1 = __builtin_amdgcn_readlane(e_l, iN1);
                int sN1 = __builtin_amdgcn_readlane(s_l, iN1);
                float    efN0 = __builtin_nontemporal_load(&ef[(size_t)eN0 * 32 + col]);
                unsigned uN0  = kvp[(size_t)sN0 * 64 + lane];
                float    efN1 = __builtin_nontemporal_load(&ef[(size_t)eN1 * 32 + col]);
                unsigned uN1  = kvp[(size_t)sN1 * 64 + lane];

                // consume edge i
                {
                    float kk = unpack_lo(uA), vv = unpack_hi(uA);
                    float p = fmaf(qv, kk, efA * gv);
                    #pragma unroll
                    for (int off = C >> 1; off; off >>= 1) p += __shfl_xor(p, off, 64);
                    float ex = __expf(p * scale);
                    racc  = fmaf(vv,  ex, racc);
                    efacc = fmaf(efA, ex, efacc);
                    rden += ex;
                }
                // consume edge i+1
                if (i + 1 < rem) {
                    float kk = unpack_lo(uB), vv = unpack_hi(uB);
                    float p = fmaf(qv, kk, efB * gv);
                    #pragma unroll
                    for (int off = C >> 1; off; off >>= 1) p += __shfl_xor(p, off, 64);
                    float ex = __expf(p * scale);
                    racc  = fmaf(vv,  ex, racc);
                    efacc = fmaf(efB, ex, efacc);
                    rden += ex;
                }

                efA = efN0; uA = uN0;
                efB = efN1; uB = uN1;
            }
        }

        // finalize: (racc + efacc @ We) / rden + skip
        exl[wslot][lane] = efacc;
        float mv = 0.f;
        #pragma unroll 8
        for (int j = 0; j < 32; ++j)
            mv = fmaf(exl[wslot][hsel * 32 + j], Wel[j * 64 + lane], mv);
        float val = (racc + mv) / (rden + 1e-16f)
                  + __builtin_nontemporal_load(&sk[(size_t)d * 64 + lane]);
        if (do_relu) val = fmaxf(val, 0.f);
        __builtin_nontemporal_store(val, &out[(size_t)d * 64 + lane]);
    }
}

extern "C" void kernel_launch(void* const* d_in, const int* in_sizes, int n_in,
                              void* d_out, int out_size, void* d_ws, size_t ws_size,
                              hipStream_t stream) {
    const float* x   = (const float*)d_in[0];
    const int*   ei  = (const int*)d_in[1];
    const float* ef  = (const float*)d_in[2];
    const float* Wq1 = (const float*)d_in[3];  const float* bq1 = (const float*)d_in[4];
    const float* Wk1 = (const float*)d_in[5];  const float* bk1 = (const float*)d_in[6];
    const float* Wv1 = (const float*)d_in[7];  const float* bv1 = (const float*)d_in[8];
    const float* We1 = (const float*)d_in[9];
    const float* Ws1 = (const float*)d_in[10]; const float* bs1 = (const float*)d_in[11];
    const float* Wq2 = (const float*)d_in[12]; const float* bq2 = (const float*)d_in[13];
    const float* Wk2 = (const float*)d_in[14]; const float* bk2 = (const float*)d_in[15];
    const float* Wv2 = (const float*)d_in[16]; const float* bv2 = (const float*)d_in[17];
    const float* We2 = (const float*)d_in[18];
    const float* Ws2 = (const float*)d_in[19]; const float* bs2 = (const float*)d_in[20];
    float* out = (float*)d_out;

    const int N = N_NODES, E = N_EDGES;
    size_t NF = (size_t)N * 64;
    float* ws = (float*)d_ws;
    float* qg    = ws;                      // N*128 (q | g interleaved, fp32)
    float* kv    = qg + 2 * NF;             // N*128 (k | v interleaved, fp32)
    float* sk    = kv + 2 * NF;             // N*64
    unsigned* kvp = (unsigned*)(sk + NF);   // N*64 (bf16 k|v packed)
    float* Wg1   = (float*)(kvp + NF);      // 128*64
    float* bg1   = Wg1 + 128 * 64;          // 64
    float* Wg2   = bg1 + 64;                // 64*64
    float* bg2   = Wg2 + 64 * 64;           // 64
    int* cnt     = (int*)(bg2 + 64);        // N
    int* excl    = cnt + N;                 // N
    int* bsum    = excl + N;                // 128
    int* rowptr  = bsum + 128;              // N+1
    int* cursor  = rowptr + N + 1;          // N
    int2* es     = (int2*)(cursor + N);     // E (edge id | src)
    float* h1    = out;                     // layer-1 output aliases d_out

    const int* src = ei;
    const int* dst = ei + E;

    dim3 b256(256);
    int gN    = (N + 255) / 256;
    int gN1   = (N + 1 + 255) / 256;
    int gE    = (E + 255) / 256;
    int gGemm = ((N + 127) / 128) * 5;      // node-tiles x 5 weight sets
    int gPack = (N * 16 + 255) / 256;
    int gEdge = 2048;                       // 8192 persistent waves
    int nScanB = (N + 1023) / 1024;         // 98

    // ---------------- CSR build (shared by both layers) ----------------
    hipLaunchKernelGGL(zero_int, dim3(gN), b256, 0, stream, cnt, N);
    hipLaunchKernelGGL(hist_kernel, dim3(gE), b256, 0, stream, dst, cnt);
    hipLaunchKernelGGL(scan1, dim3(nScanB), b256, 0, stream, cnt, excl, bsum, N);
    hipLaunchKernelGGL(scan2, dim3(1), dim3(128), 0, stream, bsum, nScanB);
    hipLaunchKernelGGL(scan3, dim3(gN1), b256, 0, stream, excl, bsum, rowptr, cursor, N);
    hipLaunchKernelGGL(scatter_kernel, dim3(gE), b256, 0, stream, dst, src, cursor, es);

    // ---------------- weight contractions (one launch, 2 blocks) ----------------
    hipLaunchKernelGGL(wg_build_both, dim3(2), b256, 0, stream,
                       Wq1, bq1, We1, Wg1, bg1, Wq2, bq2, We2, Wg2, bg2);

    // ---------------- layer 1: H=2, C=32, K=128 ----------------
    hipLaunchKernelGGL((node_gemm<128>), dim3(gGemm), b256, 0, stream, x,
                       Wq1, bq1, Wk1, bk1, Wv1, bv1, Ws1, bs1, Wg1, bg1,
                       qg, kv, sk, N);
    hipLaunchKernelGGL(pack_kv, dim3(gPack), b256, 0, stream, kv, kvp);
    hipLaunchKernelGGL((edge_csr<32, 16>), dim3(gEdge), b256, 0, stream,
                       rowptr, es, ef, We1, qg, kvp, sk, h1,
                       0.17677669529663687f, 1);

    // ---------------- layer 2: H=1, C=64, K=64 ----------------
    hipLaunchKernelGGL((node_gemm<64>), dim3(gGemm), b256, 0, stream, h1,
                       Wq2, bq2, Wk2, bk2, Wv2, bv2, Ws2, bs2, Wg2, bg2,
                       qg, kv, sk, N);
    hipLaunchKernelGGL(pack_kv, dim3(gPack), b256, 0, stream, kv, kvp);
    hipLaunchKernelGGL((edge_csr<64, 16>), dim3(gEdge), b256, 0, stream,
                       rowptr, es, ef, We2, qg, kvp, sk, out,
                       0.125f, 0);
}

// Round 11
// 418.911 us; speedup vs baseline: 12.2634x; 1.3081x over previous
//
#include <hip/hip_runtime.h>
#include <cstdint>
#include <cstddef>

typedef unsigned short ushort_t;
typedef __attribute__((ext_vector_type(8))) short short8;   // 8 bf16 (4 VGPRs)
typedef __attribute__((ext_vector_type(4))) float f32x4;    // MFMA acc

// Problem constants (from reference)
constexpr int N_NODES = 100000;
constexpr int N_EDGES = 1000000;

// ---- bf16 pack/unpack (RNE) ----
__device__ __forceinline__ unsigned bf16rne(float f) {
    unsigned u = __float_as_uint(f);
    return (u + 0x7FFFu + ((u >> 16) & 1u)) >> 16;
}
__device__ __forceinline__ unsigned pack2(float lo, float hi) {
    return bf16rne(lo) | (bf16rne(hi) << 16);
}
__device__ __forceinline__ float unpack_lo(unsigned u) { return __uint_as_float(u << 16); }
__device__ __forceinline__ float unpack_hi(unsigned u) { return __uint_as_float(u & 0xFFFF0000u); }

// ============================ CSR build ============================
__global__ void zero_int(int* __restrict__ p, int n) {
    int i = blockIdx.x * blockDim.x + threadIdx.x;
    if (i < n) p[i] = 0;
}

__global__ void hist_kernel(const int* __restrict__ dst, int* __restrict__ cnt) {
    int i = blockIdx.x * blockDim.x + threadIdx.x;
    if (i < N_EDGES) atomicAdd(&cnt[dst[i]], 1);
}

__global__ __launch_bounds__(256) void scan1(const int* __restrict__ cnt,
    int* __restrict__ excl, int* __restrict__ bsum, int n) {
    __shared__ int sh[256];
    int b = blockIdx.x, t = threadIdx.x;
    int base = b * 1024 + t * 4;
    int v0 = (base + 0 < n) ? cnt[base + 0] : 0;
    int v1 = (base + 1 < n) ? cnt[base + 1] : 0;
    int v2 = (base + 2 < n) ? cnt[base + 2] : 0;
    int v3 = (base + 3 < n) ? cnt[base + 3] : 0;
    int s = v0 + v1 + v2 + v3;
    sh[t] = s;
    __syncthreads();
    for (int off = 1; off < 256; off <<= 1) {
        int val = (t >= off) ? sh[t - off] : 0;
        __syncthreads();
        sh[t] += val;
        __syncthreads();
    }
    int prefix = sh[t] - s;
    if (t == 255) bsum[b] = sh[255];
    if (base + 0 < n) excl[base + 0] = prefix;
    if (base + 1 < n) excl[base + 1] = prefix + v0;
    if (base + 2 < n) excl[base + 2] = prefix + v0 + v1;
    if (base + 3 < n) excl[base + 3] = prefix + v0 + v1 + v2;
}

__global__ __launch_bounds__(128) void scan2(int* __restrict__ bsum, int nb) {
    __shared__ int sh[128];
    int t = threadIdx.x;
    int v = (t < nb) ? bsum[t] : 0;
    sh[t] = v;
    __syncthreads();
    for (int off = 1; off < 128; off <<= 1) {
        int val = (t >= off) ? sh[t - off] : 0;
        __syncthreads();
        sh[t] += val;
        __syncthreads();
    }
    if (t < nb) bsum[t] = sh[t] - v;
}

__global__ void scan3(const int* __restrict__ excl, const int* __restrict__ bsum,
                      int* __restrict__ rowptr, int* __restrict__ cursor, int n) {
    int i = blockIdx.x * blockDim.x + threadIdx.x;
    if (i < n) { int r = excl[i] + bsum[i >> 10]; rowptr[i] = r; cursor[i] = r; }
    if (i == n) rowptr[n] = N_EDGES;
}

__global__ void scatter_kernel(const int* __restrict__ dst, const int* __restrict__ src,
                               int* __restrict__ cursor, int2* __restrict__ es) {
    int e = blockIdx.x * blockDim.x + threadIdx.x;
    if (e < N_EDGES) {
        int p = atomicAdd(&cursor[dst[e]], 1);
        es[p] = make_int2(e, src[e]);
    }
}

// ============================ Wg build (both layers, one launch) ============================
template<int KDIM, int H>
__device__ void wg_dev(const float* __restrict__ Wq, const float* __restrict__ bq,
                       const float* __restrict__ We,
                       float* __restrict__ Wg, float* __restrict__ bg) {
    __shared__ float wq[KDIM * 64];
    __shared__ float we[32 * 64];
    int t = threadIdx.x;
    for (int i = t; i < KDIM * 64; i += 256) wq[i] = Wq[i];
    for (int i = t; i < 32 * 64; i += 256) we[i] = We[i];
    __syncthreads();
    for (int idx = t; idx < KDIM * 64; idx += 256) {
        int K = idx >> 6, col = idx & 63;
        float s = 0.f;
        if (H == 2) {
            int h = col >> 5, j = col & 31;
            #pragma unroll 8
            for (int c = 0; c < 32; ++c)
                s = fmaf(wq[K * 64 + h * 32 + c], we[j * 64 + h * 32 + c], s);
        } else {
            int j = col;
            if (j < 32) {
                #pragma unroll 8
                for (int c = 0; c < 64; ++c)
                    s = fmaf(wq[K * 64 + c], we[j * 64 + c], s);
            }
        }
        Wg[idx] = s;
    }
    if (t < 64) {
        float s = 0.f;
        if (H == 2) {
            int h = t >> 5, j = t & 31;
            for (int c = 0; c < 32; ++c)
                s = fmaf(bq[h * 32 + c], we[j * 64 + h * 32 + c], s);
        } else {
            if (t < 32)
                for (int c = 0; c < 64; ++c)
                    s = fmaf(bq[c], we[t * 64 + c], s);
        }
        bg[t] = s;
    }
}

__global__ __launch_bounds__(256) void wg_build_both(
    const float* __restrict__ Wq1, const float* __restrict__ bq1,
    const float* __restrict__ We1, float* __restrict__ Wg1, float* __restrict__ bg1,
    const float* __restrict__ Wq2, const float* __restrict__ bq2,
    const float* __restrict__ We2, float* __restrict__ Wg2, float* __restrict__ bg2)
{
    if (blockIdx.x == 0) wg_dev<128, 2>(Wq1, bq1, We1, Wg1, bg1);
    else                 wg_dev<64, 1>(Wq2, bq2, We2, Wg2, bg2);
}

// ============================ weight transpose+bf16 prep ============================
// Wtb[l] : [320][K] bf16, col-major-per-matrix concat {q,g,k,v,s}; bcat fp32 [320].
__device__ __forceinline__ const float* sel5(int m, const float* a, const float* b,
    const float* c, const float* d, const float* e) {
    switch (m) { case 0: return a; case 1: return b; case 2: return c;
                 case 3: return d; default: return e; }
}

__global__ __launch_bounds__(256) void prep_weights(
    const float* Wq1, const float* Wg1, const float* Wk1, const float* Wv1, const float* Ws1,
    const float* bq1, const float* bg1, const float* bk1, const float* bv1, const float* bs1,
    const float* Wq2, const float* Wg2, const float* Wk2, const float* Wv2, const float* Ws2,
    const float* bq2, const float* bg2, const float* bk2, const float* bv2, const float* bs2,
    ushort_t* Wtb1, float* bcat1, ushort_t* Wtb2, float* bcat2)
{
    const int T1 = 320 * 128, T2 = 320 * 64;
    int stride = gridDim.x * blockDim.x;
    for (int i = blockIdx.x * blockDim.x + threadIdx.x; i < T1 + T2 + 640; i += stride) {
        if (i < T1) {
            int col = i / 128, kk = i % 128;
            int m = col >> 6, c = col & 63;
            const float* W = sel5(m, Wq1, Wg1, Wk1, Wv1, Ws1);
            Wtb1[i] = (ushort_t)bf16rne(W[kk * 64 + c]);
        } else if (i < T1 + T2) {
            int j = i - T1;
            int col = j / 64, kk = j % 64;
            int m = col >> 6, c = col & 63;
            const float* W = sel5(m, Wq2, Wg2, Wk2, Wv2, Ws2);
            Wtb2[j] = (ushort_t)bf16rne(W[kk * 64 + c]);
        } else {
            int j = i - T1 - T2;
            if (j < 320) {
                const float* b = sel5(j >> 6, bq1, bg1, bk1, bv1, bs1);
                bcat1[j] = b[j & 63];
            } else {
                j -= 320;
                const float* b = sel5(j >> 6, bq2, bg2, bk2, bv2, bs2);
                bcat2[j] = b[j & 63];
            }
        }
    }
}

// ============================ MFMA node GEMM ============================
// M=100000 (=32*3125, no tail), N=320 (5 matrices x 64), K in {128,64}, bf16 MFMA.
// Block = 32 rows; wave w owns col-tile w (cols 16w..16w+15) of EVERY matrix, so
// q&g / k&v for one (row,col) are in the same lane -> pack in-register.
// A: fp32 (layer1 x) or bf16 (layer2 h1b) staged into padded LDS as bf16.
// Frag layouts (guide §3, m89-verified D): A row=lane&15,k=(lane>>4)*8+j;
// B col=lane&15 (from Wtb[col][k]); D col=lane&15,row=(lane>>4)*4+reg.
template<int K, typename TIN>
__global__ __launch_bounds__(256) void gemm_mfma(
    const TIN* __restrict__ xin,          // [N][K]
    const ushort_t* __restrict__ Wtb,     // [320][K] bf16
    const float* __restrict__ bcat,       // [320]
    unsigned* __restrict__ qgp,           // [N][64] pack(q,g)
    unsigned* __restrict__ kvp,           // [N][64] pack(k,v)
    float* __restrict__ sk)               // [N][64]
{
    constexpr int KP = K + 8;             // +16B pad: frag reads 2-way conflict (free)
    __shared__ ushort_t As[32][KP];

    int t = threadIdx.x;
    int lane = t & 63, w = t >> 6;
    int m0 = blockIdx.x * 32;
    int cl = lane & 15;                   // col within tile / row within tile
    int q4 = lane >> 4;                   // quad
    int col = w * 16 + cl;                // column within one 64-col matrix

    // ---- B fragments: 5 matrices x K/32 k-steps, register-resident ----
    short8 bfrag[5][K / 32];
    #pragma unroll
    for (int m = 0; m < 5; ++m)
        #pragma unroll
        for (int ks = 0; ks < K / 32; ++ks)
            bfrag[m][ks] = *(const short8*)&Wtb[(size_t)(m * 64 + col) * K + ks * 32 + q4 * 8];
    float bias[5];
    #pragma unroll
    for (int m = 0; m < 5; ++m) bias[m] = bcat[m * 64 + col];

    // ---- stage A tile to LDS (convert to bf16 if fp32 input) ----
    if constexpr (sizeof(TIN) == 4) {
        constexpr int C4 = K / 4;
        #pragma unroll
        for (int it = 0; it < 32 * C4 / 256; ++it) {
            int idx = it * 256 + t;
            int row = idx / C4, c4 = idx % C4;
            float4 xv = *(const float4*)&((const float*)xin)[(size_t)(m0 + row) * K + c4 * 4];
            *(uint2*)&As[row][c4 * 4] = make_uint2(pack2(xv.x, xv.y), pack2(xv.z, xv.w));
        }
    } else {
        constexpr int C4 = K / 4;
        #pragma unroll
        for (int it = 0; it < 32 * C4 / 256; ++it) {
            int idx = it * 256 + t;
            int row = idx / C4, c4 = idx % C4;
            uint2 u = *(const uint2*)&((const ushort_t*)xin)[(size_t)(m0 + row) * K + c4 * 4];
            *(uint2*)&As[row][c4 * 4] = u;
        }
    }
    __syncthreads();

    // ---- MFMA: 2 row-tiles x 5 matrices ----
    f32x4 acc[5][2];
    f32x4 zero = {0.f, 0.f, 0.f, 0.f};
    #pragma unroll
    for (int m = 0; m < 5; ++m) { acc[m][0] = zero; acc[m][1] = zero; }

    #pragma unroll
    for (int ks = 0; ks < K / 32; ++ks) {
        short8 a0 = *(const short8*)&As[cl][ks * 32 + q4 * 8];
        short8 a1 = *(const short8*)&As[16 + cl][ks * 32 + q4 * 8];
        #pragma unroll
        for (int m = 0; m < 5; ++m) {
            acc[m][0] = __builtin_amdgcn_mfma_f32_16x16x32_bf16(a0, bfrag[m][ks], acc[m][0], 0, 0, 0);
            acc[m][1] = __builtin_amdgcn_mfma_f32_16x16x32_bf16(a1, bfrag[m][ks], acc[m][1], 0, 0, 0);
        }
    }

    // ---- epilogue: bias, pack, store ----
    #pragma unroll
    for (int rt = 0; rt < 2; ++rt) {
        #pragma unroll
        for (int r = 0; r < 4; ++r) {
            int row = m0 + rt * 16 + q4 * 4 + r;
            float qv = acc[0][rt][r] + bias[0];
            float gv = acc[1][rt][r] + bias[1];
            float kk = acc[2][rt][r] + bias[2];
            float vv = acc[3][rt][r] + bias[3];
            float sv = acc[4][rt][r] + bias[4];
            qgp[(size_t)row * 64 + col] = pack2(qv, gv);
            kvp[(size_t)row * 64 + col] = pack2(kk, vv);
            sk [(size_t)row * 64 + col] = sv;
        }
    }
}

// ============================ CSR edge pass v7 ============================
// alpha = scale*(q.k[s] + ef.g[d]);  out_pre = (Σ ex*v[s] + (Σ ex*ef)@We)/Σ ex
// qgp/kvp bf16-packed (one dword per channel-pair). Depth-2 pipeline; nt hints.
// OT = ushort_t (layer1 -> bf16 h1b) or float (layer2 -> d_out).
template<int C, int CHUNK, typename OT>
__global__ __launch_bounds__(256) void edge_csr(
    const int* __restrict__ rowptr, const int2* __restrict__ es,
    const float* __restrict__ ef, const float* __restrict__ We,
    const unsigned* __restrict__ qgp, const unsigned* __restrict__ kvp,
    const float* __restrict__ sk, OT* __restrict__ out,
    float scale, int do_relu)
{
    __shared__ float Wel[32 * 64];
    __shared__ float exl[4][64];
    int t = threadIdx.x;
    for (int i = t; i < 32 * 64; i += 256) Wel[i] = We[i];
    __syncthreads();

    int lane  = t & 63;
    int wslot = t >> 6;
    int col   = lane & 31;
    int hsel  = (C == 64) ? 0 : (lane >> 5);

    int wid = blockIdx.x * 4 + wslot;
    int nw  = gridDim.x * 4;

    for (int d0 = wid; d0 < N_NODES; d0 += nw) {
        int d = __builtin_amdgcn_readfirstlane(d0);
        int r0 = rowptr[d], r1 = rowptr[d + 1];
        unsigned uqg = __builtin_nontemporal_load(&qgp[(size_t)d * 64 + lane]);
        float qv = unpack_lo(uqg), gv = unpack_hi(uqg);
        float racc = 0.f, efacc = 0.f, rden = 0.f;

        for (int c0 = r0; c0 < r1; c0 += CHUNK) {
            int rem = min(CHUNK, r1 - c0);
            long long ll = (lane < rem)
                ? __builtin_nontemporal_load((const long long*)&es[c0 + lane]) : 0LL;
            int e_l = (int)ll;
            int s_l = (int)(ll >> 32);

            int i1 = min(1, rem - 1);
            int eA = __builtin_amdgcn_readlane(e_l, 0);
            int sA = __builtin_amdgcn_readlane(s_l, 0);
            int eB = __builtin_amdgcn_readlane(e_l, i1);
            int sB = __builtin_amdgcn_readlane(s_l, i1);
            float    efA = __builtin_nontemporal_load(&ef[(size_t)eA * 32 + col]);
            unsigned uA  = kvp[(size_t)sA * 64 + lane];
            float    efB = __builtin_nontemporal_load(&ef[(size_t)eB * 32 + col]);
            unsigned uB  = kvp[(size_t)sB * 64 + lane];

            for (int i = 0; i < rem; i += 2) {
                int iN0 = min(i + 2, rem - 1);
                int iN1 = min(i + 3, rem - 1);
                int eN0 = __builtin_amdgcn_readlane(e_l, iN0);
                int sN0 = __builtin_amdgcn_readlane(s_l, iN0);
                int eN1 = __builtin_amdgcn_readlane(e_l, iN1);
                int sN1 = __builtin_amdgcn_readlane(s_l, iN1);
                float    efN0 = __builtin_nontemporal_load(&ef[(size_t)eN0 * 32 + col]);
                unsigned uN0  = kvp[(size_t)sN0 * 64 + lane];
                float    efN1 = __builtin_nontemporal_load(&ef[(size_t)eN1 * 32 + col]);
                unsigned uN1  = kvp[(size_t)sN1 * 64 + lane];

                {
                    float kk = unpack_lo(uA), vv = unpack_hi(uA);
                    float p = fmaf(qv, kk, efA * gv);
                    #pragma unroll
                    for (int off = C >> 1; off; off >>= 1) p += __shfl_xor(p, off, 64);
                    float ex = __expf(p * scale);
                    racc  = fmaf(vv,  ex, racc);
                    efacc = fmaf(efA, ex, efacc);
                    rden += ex;
                }
                if (i + 1 < rem) {
                    float kk = unpack_lo(uB), vv = unpack_hi(uB);
                    float p = fmaf(qv, kk, efB * gv);
                    #pragma unroll
                    for (int off = C >> 1; off; off >>= 1) p += __shfl_xor(p, off, 64);
                    float ex = __expf(p * scale);
                    racc  = fmaf(vv,  ex, racc);
                    efacc = fmaf(efB, ex, efacc);
                    rden += ex;
                }

                efA = efN0; uA = uN0;
                efB = efN1; uB = uN1;
            }
        }

        exl[wslot][lane] = efacc;
        float mv = 0.f;
        #pragma unroll 8
        for (int j = 0; j < 32; ++j)
            mv = fmaf(exl[wslot][hsel * 32 + j], Wel[j * 64 + lane], mv);
        float val = (racc + mv) / (rden + 1e-16f)
                  + __builtin_nontemporal_load(&sk[(size_t)d * 64 + lane]);
        if (do_relu) val = fmaxf(val, 0.f);
        if constexpr (sizeof(OT) == 4)
            __builtin_nontemporal_store(val, &out[(size_t)d * 64 + lane]);
        else
            out[(size_t)d * 64 + lane] = (OT)bf16rne(val);
    }
}

extern "C" void kernel_launch(void* const* d_in, const int* in_sizes, int n_in,
                              void* d_out, int out_size, void* d_ws, size_t ws_size,
                              hipStream_t stream) {
    const float* x   = (const float*)d_in[0];
    const int*   ei  = (const int*)d_in[1];
    const float* ef  = (const float*)d_in[2];
    const float* Wq1 = (const float*)d_in[3];  const float* bq1 = (const float*)d_in[4];
    const float* Wk1 = (const float*)d_in[5];  const float* bk1 = (const float*)d_in[6];
    const float* Wv1 = (const float*)d_in[7];  const float* bv1 = (const float*)d_in[8];
    const float* We1 = (const float*)d_in[9];
    const float* Ws1 = (const float*)d_in[10]; const float* bs1 = (const float*)d_in[11];
    const float* Wq2 = (const float*)d_in[12]; const float* bq2 = (const float*)d_in[13];
    const float* Wk2 = (const float*)d_in[14]; const float* bk2 = (const float*)d_in[15];
    const float* Wv2 = (const float*)d_in[16]; const float* bv2 = (const float*)d_in[17];
    const float* We2 = (const float*)d_in[18];
    const float* Ws2 = (const float*)d_in[19]; const float* bs2 = (const float*)d_in[20];
    float* out = (float*)d_out;

    const int N = N_NODES, E = N_EDGES;
    size_t NF = (size_t)N * 64;
    unsigned* qgp  = (unsigned*)d_ws;           // N*64 u32 (bf16 q|g)
    unsigned* kvp  = qgp + NF;                  // N*64 u32 (bf16 k|v)
    float*    sk   = (float*)(kvp + NF);        // N*64 f32
    ushort_t* h1b  = (ushort_t*)(sk + NF);      // N*64 bf16 (layer-1 output)
    float*    Wg1  = (float*)(h1b + NF);        // 128*64
    float*    bg1  = Wg1 + 128 * 64;            // 64
    float*    Wg2  = bg1 + 64;                  // 64*64
    float*    bg2  = Wg2 + 64 * 64;             // 64
    ushort_t* Wtb1 = (ushort_t*)(bg2 + 64);     // 320*128 bf16
    float*    bcat1= (float*)(Wtb1 + 320 * 128);// 320
    ushort_t* Wtb2 = (ushort_t*)(bcat1 + 320);  // 320*64 bf16
    float*    bcat2= (float*)(Wtb2 + 320 * 64); // 320
    int* cnt    = (int*)(bcat2 + 320);          // N
    int* excl   = cnt + N;                      // N
    int* bsum   = excl + N;                     // 128
    int* cursor = bsum + 128;                   // N
    int* rowptr = cursor + N;                   // N+1 (+1 pad)
    int2* es    = (int2*)(rowptr + N + 2);      // E (8B-aligned)

    const int* src = ei;
    const int* dst = ei + E;

    dim3 b256(256);
    int gN    = (N + 255) / 256;
    int gN1   = (N + 1 + 255) / 256;
    int gE    = (E + 255) / 256;
    int gGemm = N / 32;                         // 3125 exactly
    int gEdge = 2048;
    int nScanB = (N + 1023) / 1024;

    // ---------------- CSR build (shared by both layers) ----------------
    hipLaunchKernelGGL(zero_int, dim3(gN), b256, 0, stream, cnt, N);
    hipLaunchKernelGGL(hist_kernel, dim3(gE), b256, 0, stream, dst, cnt);
    hipLaunchKernelGGL(scan1, dim3(nScanB), b256, 0, stream, cnt, excl, bsum, N);
    hipLaunchKernelGGL(scan2, dim3(1), dim3(128), 0, stream, bsum, nScanB);
    hipLaunchKernelGGL(scan3, dim3(gN1), b256, 0, stream, excl, bsum, rowptr, cursor, N);
    hipLaunchKernelGGL(scatter_kernel, dim3(gE), b256, 0, stream, dst, src, cursor, es);

    // ---------------- weight prep ----------------
    hipLaunchKernelGGL(wg_build_both, dim3(2), b256, 0, stream,
                       Wq1, bq1, We1, Wg1, bg1, Wq2, bq2, We2, Wg2, bg2);
    hipLaunchKernelGGL(prep_weights, dim3(64), b256, 0, stream,
                       Wq1, Wg1, Wk1, Wv1, Ws1, bq1, bg1, bk1, bv1, bs1,
                       Wq2, Wg2, Wk2, Wv2, Ws2, bq2, bg2, bk2, bv2, bs2,
                       Wtb1, bcat1, Wtb2, bcat2);

    // ---------------- layer 1: H=2, C=32, K=128 ----------------
    hipLaunchKernelGGL((gemm_mfma<128, float>), dim3(gGemm), b256, 0, stream,
                       x, Wtb1, bcat1, qgp, kvp, sk);
    hipLaunchKernelGGL((edge_csr<32, 16, ushort_t>), dim3(gEdge), b256, 0, stream,
                       rowptr, es, ef, We1, qgp, kvp, sk, h1b,
                       0.17677669529663687f, 1);

    // ---------------- layer 2: H=1, C=64, K=64 ----------------
    hipLaunchKernelGGL((gemm_mfma<64, ushort_t>), dim3(gGemm), b256, 0, stream,
                       h1b, Wtb2, bcat2, qgp, kvp, sk);
    hipLaunchKernelGGL((edge_csr<64, 16, float>), dim3(gEdge), b256, 0, stream,
                       rowptr, es, ef, We2, qgp, kvp, sk, out,
                       0.125f, 0);
}